// Round 4
// baseline (1243.183 us; speedup 1.0000x reference)
//
#include <hip/hip_runtime.h>

// Topology encoder: 2-layer GCN (N=100k nodes, E=3.2M edges) + max/mean pool
// over B=64 graphs + 2-layer MLP. All fp32.
//
// CSR-by-dst built per call: hist -> scan -> BINNED two-phase placement
// (k_bin: coarse 128-node buckets, sequential write streams; k_place2: LDS
// cursors, bucket-local col writes). Layers are gathers (no fp32 atomics).

#define F 32
#define POOLD 64
#define SCAN_CHUNK 1024   // 256 threads x 4 elements
#define BKT 128           // nodes per coarse bucket (log2 = 7)

// ---- degree histogram over dst (fire-and-forget atomics, 4 edges/thread) ----
__global__ void k_hist(const int* __restrict__ ei, int* __restrict__ counts, int e) {
    int i = (blockIdx.x * blockDim.x + threadIdx.x) * 4;
    if (i + 4 <= e) {
        int4 d = *reinterpret_cast<const int4*>(ei + e + i);
        atomicAdd(&counts[d.x], 1);
        atomicAdd(&counts[d.y], 1);
        atomicAdd(&counts[d.z], 1);
        atomicAdd(&counts[d.w], 1);
    } else {
        for (int k = i; k < e; ++k) atomicAdd(&counts[ei[e + k]], 1);
    }
}

// ---- scan level 1 (+ fused dinv = rsqrt(deg+1)) ----
__global__ void k_scan1(const int* __restrict__ cnts, int* __restrict__ rp,
                        int* __restrict__ partial, float* __restrict__ dinv, int n) {
    __shared__ int lds[256];
    int base = blockIdx.x * SCAN_CHUNK;
    int t = threadIdx.x;
    int v[4];
    int s = 0;
#pragma unroll
    for (int j = 0; j < 4; ++j) {
        int i = base + t * 4 + j;
        v[j] = (i < n) ? cnts[i] : 0;
        if (i < n) dinv[i] = rsqrtf((float)v[j] + 1.0f);
        s += v[j];
    }
    lds[t] = s;
    __syncthreads();
    int val = s;
    for (int off = 1; off < 256; off <<= 1) {
        int other = (t >= off) ? lds[t - off] : 0;
        __syncthreads();
        val += other;
        lds[t] = val;
        __syncthreads();
    }
    int excl = val - s;
#pragma unroll
    for (int j = 0; j < 4; ++j) {
        int i = base + t * 4 + j;
        if (i < n) rp[i] = excl;
        excl += v[j];
    }
    if (t == 255) partial[blockIdx.x] = lds[255];
}

__global__ void k_scan2(int* __restrict__ partial, int nb) {
    __shared__ int lds[256];
    int t = threadIdx.x;
    int s = (t < nb) ? partial[t] : 0;
    lds[t] = s;
    __syncthreads();
    int val = s;
    for (int off = 1; off < 256; off <<= 1) {
        int other = (t >= off) ? lds[t - off] : 0;
        __syncthreads();
        val += other;
        lds[t] = val;
        __syncthreads();
    }
    if (t < nb) partial[t] = val - s;  // exclusive
}

// ---- scan level 3 (+ fused bucket-cursor init: bcur[b] = rp[b*BKT]) ----
__global__ void k_scan3(int* __restrict__ rp, const int* __restrict__ partial,
                        int* __restrict__ bcur, int n) {
    int base = blockIdx.x * SCAN_CHUNK;
    int add = partial[blockIdx.x];
    int t = threadIdx.x;
#pragma unroll
    for (int j = 0; j < 4; ++j) {
        int i = base + t * 4 + j;
        if (i < n) {
            int v = rp[i] + add;
            rp[i] = v;
            if ((i & (BKT - 1)) == 0) bcur[i >> 7] = v;
        }
    }
}

// ---- phase 1: bin edges by coarse bucket (dst>>7), packed (src<<7)|dstlow ----
__global__ void k_bin(const int* __restrict__ ei, int* __restrict__ bcur,
                      int* __restrict__ packed, int e) {
    int i = (blockIdx.x * blockDim.x + threadIdx.x) * 4;
    if (i + 4 <= e) {
        int4 s4 = *reinterpret_cast<const int4*>(ei + i);
        int4 d4 = *reinterpret_cast<const int4*>(ei + e + i);
        int p0 = atomicAdd(&bcur[d4.x >> 7], 1);
        int p1 = atomicAdd(&bcur[d4.y >> 7], 1);
        int p2 = atomicAdd(&bcur[d4.z >> 7], 1);
        int p3 = atomicAdd(&bcur[d4.w >> 7], 1);
        packed[p0] = (s4.x << 7) | (d4.x & (BKT - 1));
        packed[p1] = (s4.y << 7) | (d4.y & (BKT - 1));
        packed[p2] = (s4.z << 7) | (d4.z & (BKT - 1));
        packed[p3] = (s4.w << 7) | (d4.w & (BKT - 1));
    } else {
        for (int k = i; k < e; ++k) {
            int s = ei[k], d = ei[e + k];
            int p = atomicAdd(&bcur[d >> 7], 1);
            packed[p] = (s << 7) | (d & (BKT - 1));
        }
    }
}

// ---- phase 2: one block per bucket; LDS cursors; bucket-local col writes ----
__global__ void k_place2(const int* __restrict__ packed, const int* __restrict__ rp,
                         int* __restrict__ col, int n, int e) {
    __shared__ int cur[BKT];
    int nodeBase = blockIdx.x * BKT;
    int nNodes = min(BKT, n - nodeBase);
    if (threadIdx.x < nNodes) cur[threadIdx.x] = rp[nodeBase + threadIdx.x];
    __syncthreads();
    int start = rp[nodeBase];
    int end = (nodeBase + BKT < n) ? rp[nodeBase + BKT] : e;
    for (int i = start + threadIdx.x; i < end; i += blockDim.x) {
        int u = packed[i];
        int p = atomicAdd(&cur[u & (BKT - 1)], 1);
        col[p] = u >> 7;
    }
}

// ---- h0 = x @ W1  (K=3) ----
__global__ void k_xw1(const float* __restrict__ x, const float* __restrict__ W1,
                      float* __restrict__ h0, int n) {
    int i = blockIdx.x * blockDim.x + threadIdx.x;
    if (i >= n * F) return;
    int node = i >> 5, f = i & (F - 1);
    float x0 = x[node * 3 + 0], x1 = x[node * 3 + 1], x2 = x[node * 3 + 2];
    h0[i] = x0 * W1[f] + x1 * W1[F + f] + x2 * W1[2 * F + f];
}

// ---- g = h @ W2  (32x32) ----
__global__ void k_gemm2(const float* __restrict__ h, const float* __restrict__ W2,
                        float* __restrict__ g, int n) {
    int i = blockIdx.x * blockDim.x + threadIdx.x;
    if (i >= n * F) return;
    int node = i >> 5, f = i & (F - 1);
    const float* row = h + node * F;
    float acc = 0.0f;
#pragma unroll
    for (int k = 0; k < F; ++k) acc += row[k] * W2[k * F + f];
    g[i] = acc;
}

// ---- fused gather conv + bias + relu + pool; 8 threads/node, x4 unroll ----
// rp is exclusive-start form; row range = [rp[node], node+1<n ? rp[node+1] : e)
__global__ void k_gather(const float* __restrict__ hin, const int* __restrict__ rp,
                         const int* __restrict__ col, const float* __restrict__ dinv,
                         const float* __restrict__ bias, const int* __restrict__ batch,
                         float* __restrict__ hout,
                         float* __restrict__ psum, float* __restrict__ pmax,
                         float* __restrict__ cnt, int n, int ne, int store, int do_cnt) {
    int t = blockIdx.x * blockDim.x + threadIdx.x;
    int node = t >> 3, q = t & 7;
    if (node >= n) return;
    int start = rp[node];
    int end = (node + 1 < n) ? rp[node + 1] : ne;
    float dv = dinv[node];

    float4 acc = *reinterpret_cast<const float4*>(hin + node * F + q * 4);
    float dvv = dv * dv;
    acc.x *= dvv; acc.y *= dvv; acc.z *= dvv; acc.w *= dvv;

    int e = start;
    for (; e + 4 <= end; e += 4) {
        int s0 = col[e + 0], s1 = col[e + 1], s2 = col[e + 2], s3 = col[e + 3];
        float w0 = dinv[s0] * dv, w1 = dinv[s1] * dv,
              w2 = dinv[s2] * dv, w3 = dinv[s3] * dv;
        float4 v0 = *reinterpret_cast<const float4*>(hin + s0 * F + q * 4);
        float4 v1 = *reinterpret_cast<const float4*>(hin + s1 * F + q * 4);
        float4 v2 = *reinterpret_cast<const float4*>(hin + s2 * F + q * 4);
        float4 v3 = *reinterpret_cast<const float4*>(hin + s3 * F + q * 4);
        acc.x += v0.x * w0 + v1.x * w1 + v2.x * w2 + v3.x * w3;
        acc.y += v0.y * w0 + v1.y * w1 + v2.y * w2 + v3.y * w3;
        acc.z += v0.z * w0 + v1.z * w1 + v2.z * w2 + v3.z * w3;
        acc.w += v0.w * w0 + v1.w * w1 + v2.w * w2 + v3.w * w3;
    }
    for (; e < end; ++e) {
        int s = col[e];
        float wv = dinv[s] * dv;
        const float4 v = *reinterpret_cast<const float4*>(hin + s * F + q * 4);
        acc.x += v.x * wv; acc.y += v.y * wv; acc.z += v.z * wv; acc.w += v.w * wv;
    }

    const float4 b4 = *reinterpret_cast<const float4*>(bias + q * 4);
    float4 v;
    v.x = fmaxf(acc.x + b4.x, 0.0f);
    v.y = fmaxf(acc.y + b4.y, 0.0f);
    v.z = fmaxf(acc.z + b4.z, 0.0f);
    v.w = fmaxf(acc.w + b4.w, 0.0f);
    if (store) *reinterpret_cast<float4*>(hout + node * F + q * 4) = v;

    int b = batch[node];
    int lane = threadIdx.x & 63;
    int bFirst = __shfl(b, 0);
    int bLast  = __shfl(b, 63);
    if (bFirst == bLast) {
        float4 sv = v, mv = v;
        for (int off = 8; off < 64; off <<= 1) {
            sv.x += __shfl_down(sv.x, off);
            sv.y += __shfl_down(sv.y, off);
            sv.z += __shfl_down(sv.z, off);
            sv.w += __shfl_down(sv.w, off);
            mv.x = fmaxf(mv.x, __shfl_down(mv.x, off));
            mv.y = fmaxf(mv.y, __shfl_down(mv.y, off));
            mv.z = fmaxf(mv.z, __shfl_down(mv.z, off));
            mv.w = fmaxf(mv.w, __shfl_down(mv.w, off));
        }
        if (lane < 8) {
            float* ps = psum + b * F + lane * 4;
            atomicAdd(ps + 0, sv.x);
            atomicAdd(ps + 1, sv.y);
            atomicAdd(ps + 2, sv.z);
            atomicAdd(ps + 3, sv.w);
            int* pm = reinterpret_cast<int*>(pmax + b * F + lane * 4);
            atomicMax(pm + 0, __float_as_int(mv.x));
            atomicMax(pm + 1, __float_as_int(mv.y));
            atomicMax(pm + 2, __float_as_int(mv.z));
            atomicMax(pm + 3, __float_as_int(mv.w));
            if (do_cnt && lane == 0) atomicAdd(&cnt[b], 8.0f);
        }
    } else {
        float* ps = psum + b * F + q * 4;
        atomicAdd(ps + 0, v.x);
        atomicAdd(ps + 1, v.y);
        atomicAdd(ps + 2, v.z);
        atomicAdd(ps + 3, v.w);
        int* pm = reinterpret_cast<int*>(pmax + b * F + q * 4);
        atomicMax(pm + 0, __float_as_int(v.x));
        atomicMax(pm + 1, __float_as_int(v.y));
        atomicMax(pm + 2, __float_as_int(v.z));
        atomicMax(pm + 3, __float_as_int(v.w));
        if (do_cnt && q == 0) atomicAdd(&cnt[b], 1.0f);
    }
}

// ---- fused MLP head: one block per graph (64 threads) ----
__global__ void k_mlp(const float* __restrict__ sum1, const float* __restrict__ max1,
                      const float* __restrict__ sum2, const float* __restrict__ max2,
                      const float* __restrict__ cnt,
                      const float* __restrict__ LW1, const float* __restrict__ Lb1,
                      const float* __restrict__ LW2, const float* __restrict__ Lb2,
                      float* __restrict__ out, int outd) {
    __shared__ float zs[POOLD];
    int b = blockIdx.x, j = threadIdx.x;  // blockDim.x == 64
    float invc = 1.0f / fmaxf(cnt[b], 1.0f);
    float acc = Lb1[j];
#pragma unroll
    for (int i = 0; i < POOLD; ++i) {
        float s;
        if (i < F) s = max1[b * F + i] + max2[b * F + i];
        else       s = (sum1[b * F + i - F] + sum2[b * F + i - F]) * invc;
        acc += s * LW1[i * POOLD + j];
    }
    zs[j] = fmaxf(acc, 0.0f);
    __syncthreads();
    if (j < outd) {
        float a2 = Lb2[j];
#pragma unroll
        for (int jj = 0; jj < POOLD; ++jj) a2 += zs[jj] * LW2[jj * outd + j];
        out[b * outd + j] = a2;
    }
}

extern "C" void kernel_launch(void* const* d_in, const int* in_sizes, int n_in,
                              void* d_out, int out_size, void* d_ws, size_t ws_size,
                              hipStream_t stream) {
    const float* x    = (const float*)d_in[0];
    const int*   ei   = (const int*)d_in[1];
    const int*   batch= (const int*)d_in[2];
    const float* W1   = (const float*)d_in[3];
    const float* b1   = (const float*)d_in[4];
    const float* W2   = (const float*)d_in[5];
    const float* b2   = (const float*)d_in[6];
    const float* LW1  = (const float*)d_in[7];
    const float* Lb1  = (const float*)d_in[8];
    const float* LW2  = (const float*)d_in[9];
    const float* Lb2  = (const float*)d_in[10];
    float* out = (float*)d_out;

    const int N = in_sizes[0] / 3;
    const int E = in_sizes[1] / 2;
    const int OUTD = in_sizes[10];
    const int B = out_size / OUTD;
    const int poolsz = 4 * B * F + B;
    const int NB = (N + BKT - 1) / BKT;   // coarse buckets

    // ---- workspace layout: [counts][pools] contiguous for one memset ----
    char* p = (char*)d_ws;
    int* counts = (int*)p;            p += (size_t)N * 4;
    float* pools= (float*)p;          p += (size_t)poolsz * 4;
    int* rowptr = (int*)p;            p += (size_t)N * 4;
    int* col    = (int*)p;            p += (size_t)E * 4;
    int* partial= (int*)p;            p += 256 * 4;
    int* bcur   = (int*)p;            p += (size_t)NB * 4;
    float* dinv = (float*)p;          p += (size_t)N * 4;
    float* buf0 = (float*)p;          p += (size_t)N * F * 4;
    float* buf1 = (float*)p;          p += (size_t)N * F * 4;
    int* packed = (int*)buf0;         // aliased: consumed before k_xw1 writes buf0
    float* sum1 = pools;
    float* max1 = sum1 + B * F;
    float* sum2 = max1 + B * F;
    float* max2 = sum2 + B * F;
    float* cnt  = max2 + B * F;

    const int BS = 256;
    auto g1 = [&](long long n) { return (int)((n + BS - 1) / BS); };
    const int nScanBlocks = (N + SCAN_CHUNK - 1) / SCAN_CHUNK;

    // CSR build + norms
    hipMemsetAsync(counts, 0, (size_t)(N + poolsz) * 4, stream);
    k_hist<<<g1((E + 3) / 4), BS, 0, stream>>>(ei, counts, E);
    k_scan1<<<nScanBlocks, 256, 0, stream>>>(counts, rowptr, partial, dinv, N);
    k_scan2<<<1, 256, 0, stream>>>(partial, nScanBlocks);
    k_scan3<<<nScanBlocks, 256, 0, stream>>>(rowptr, partial, bcur, N);
    k_bin<<<g1((E + 3) / 4), BS, 0, stream>>>(ei, bcur, packed, E);
    k_place2<<<NB, BS, 0, stream>>>(packed, rowptr, col, N, E);

    // layer 1
    k_xw1<<<g1((long long)N * F), BS, 0, stream>>>(x, W1, buf0, N);
    k_gather<<<g1((long long)N * 8), BS, 0, stream>>>(buf0, rowptr, col, dinv, b1,
                                                      batch, buf1, sum1, max1, cnt,
                                                      N, E, /*store=*/1, /*do_cnt=*/1);
    // layer 2
    k_gemm2<<<g1((long long)N * F), BS, 0, stream>>>(buf1, W2, buf0, N);
    k_gather<<<g1((long long)N * 8), BS, 0, stream>>>(buf0, rowptr, col, dinv, b2,
                                                      batch, buf1, sum2, max2, cnt,
                                                      N, E, /*store=*/0, /*do_cnt=*/0);

    // MLP head
    k_mlp<<<B, 64, 0, stream>>>(sum1, max1, sum2, max2, cnt,
                                LW1, Lb1, LW2, Lb2, out, OUTD);
}

// Round 5
// 736.255 us; speedup vs baseline: 1.6885x; 1.6885x over previous
//
#include <hip/hip_runtime.h>

// Topology encoder: 2-layer GCN (N=100k nodes, E=3.2M edges) + max/mean pool
// over B=64 graphs + 2-layer MLP. All fp32.
//
// CSR-by-dst built per call: hist (node + bucket/shard counts) -> scan ->
// sharded binning (8 cursor shards per bucket, shard == block-group == XCD
// round-robin so each sub-region is written from one L2) -> LDS-cursor
// placement. Layers are gathers (no fp32 atomics). Pool atomics wave-reduced.

#define F 32
#define POOLD 64
#define SCAN_CHUNK 1024   // 256 threads x 4 elements
#define BKT 128           // nodes per coarse bucket (log2 = 7)
#define NSH 8             // cursor shards per bucket (~ XCD count)
#define EPB 4096          // edges per k_bin block (log2 = 12)

// ---- histogram: per-node counts + per-(bucket,shard) counts ----
__global__ void k_hist(const int* __restrict__ ei, int* __restrict__ counts,
                       int* __restrict__ shist, int e) {
    int i = (blockIdx.x * blockDim.x + threadIdx.x) * 4;
    if (i + 4 <= e) {
        int4 d = *reinterpret_cast<const int4*>(ei + e + i);
        atomicAdd(&counts[d.x], 1);
        atomicAdd(&counts[d.y], 1);
        atomicAdd(&counts[d.z], 1);
        atomicAdd(&counts[d.w], 1);
        atomicAdd(&shist[((d.x >> 7) << 3) | (((i + 0) >> 12) & (NSH - 1))], 1);
        atomicAdd(&shist[((d.y >> 7) << 3) | (((i + 1) >> 12) & (NSH - 1))], 1);
        atomicAdd(&shist[((d.z >> 7) << 3) | (((i + 2) >> 12) & (NSH - 1))], 1);
        atomicAdd(&shist[((d.w >> 7) << 3) | (((i + 3) >> 12) & (NSH - 1))], 1);
    } else {
        for (int k = i; k < e; ++k) {
            int d = ei[e + k];
            atomicAdd(&counts[d], 1);
            atomicAdd(&shist[((d >> 7) << 3) | ((k >> 12) & (NSH - 1))], 1);
        }
    }
}

// ---- scan level 1 (+ fused dinv = rsqrt(deg+1)) ----
__global__ void k_scan1(const int* __restrict__ cnts, int* __restrict__ rp,
                        int* __restrict__ partial, float* __restrict__ dinv, int n) {
    __shared__ int lds[256];
    int base = blockIdx.x * SCAN_CHUNK;
    int t = threadIdx.x;
    int v[4];
    int s = 0;
#pragma unroll
    for (int j = 0; j < 4; ++j) {
        int i = base + t * 4 + j;
        v[j] = (i < n) ? cnts[i] : 0;
        if (i < n) dinv[i] = rsqrtf((float)v[j] + 1.0f);
        s += v[j];
    }
    lds[t] = s;
    __syncthreads();
    int val = s;
    for (int off = 1; off < 256; off <<= 1) {
        int other = (t >= off) ? lds[t - off] : 0;
        __syncthreads();
        val += other;
        lds[t] = val;
        __syncthreads();
    }
    int excl = val - s;
#pragma unroll
    for (int j = 0; j < 4; ++j) {
        int i = base + t * 4 + j;
        if (i < n) rp[i] = excl;
        excl += v[j];
    }
    if (t == 255) partial[blockIdx.x] = lds[255];
}

__global__ void k_scan2(int* __restrict__ partial, int nb) {
    __shared__ int lds[256];
    int t = threadIdx.x;
    int s = (t < nb) ? partial[t] : 0;
    lds[t] = s;
    __syncthreads();
    int val = s;
    for (int off = 1; off < 256; off <<= 1) {
        int other = (t >= off) ? lds[t - off] : 0;
        __syncthreads();
        val += other;
        lds[t] = val;
        __syncthreads();
    }
    if (t < nb) partial[t] = val - s;  // exclusive
}

__global__ void k_scan3(int* __restrict__ rp, const int* __restrict__ partial, int n) {
    int base = blockIdx.x * SCAN_CHUNK;
    int add = partial[blockIdx.x];
    int t = threadIdx.x;
#pragma unroll
    for (int j = 0; j < 4; ++j) {
        int i = base + t * 4 + j;
        if (i < n) rp[i] += add;
    }
}

// ---- per-(bucket,shard) cursors: scur[b][s] = rp[b*BKT] + prefix(shist[b][0..s)) ----
__global__ void k_scur(const int* __restrict__ rp, const int* __restrict__ shist,
                       int* __restrict__ scur, int nbuck) {
    int b = blockIdx.x * blockDim.x + threadIdx.x;
    if (b >= nbuck) return;
    int acc = rp[b * BKT];
#pragma unroll
    for (int s = 0; s < NSH; ++s) {
        scur[b * NSH + s] = acc;
        acc += shist[b * NSH + s];
    }
}

// ---- phase 1: bin edges; cursor shard = block group (XCD round-robin) ----
__global__ void k_bin(const int* __restrict__ ei, int* __restrict__ scur,
                      int* __restrict__ packed, int e) {
    int sh = blockIdx.x & (NSH - 1);
    int base = blockIdx.x * EPB;
#pragma unroll
    for (int k = 0; k < 4; ++k) {
        int i = base + (k * 256 + threadIdx.x) * 4;
        if (i + 4 <= e) {
            int4 s4 = *reinterpret_cast<const int4*>(ei + i);
            int4 d4 = *reinterpret_cast<const int4*>(ei + e + i);
            int p0 = atomicAdd(&scur[((d4.x >> 7) << 3) | sh], 1);
            int p1 = atomicAdd(&scur[((d4.y >> 7) << 3) | sh], 1);
            int p2 = atomicAdd(&scur[((d4.z >> 7) << 3) | sh], 1);
            int p3 = atomicAdd(&scur[((d4.w >> 7) << 3) | sh], 1);
            packed[p0] = (s4.x << 7) | (d4.x & (BKT - 1));
            packed[p1] = (s4.y << 7) | (d4.y & (BKT - 1));
            packed[p2] = (s4.z << 7) | (d4.z & (BKT - 1));
            packed[p3] = (s4.w << 7) | (d4.w & (BKT - 1));
        } else {
            for (int j = i; j < e && j < i + 4; ++j) {
                int s = ei[j], d = ei[e + j];
                int p = atomicAdd(&scur[((d >> 7) << 3) | sh], 1);
                packed[p] = (s << 7) | (d & (BKT - 1));
            }
        }
    }
}

// ---- phase 2: one block per bucket; LDS cursors; bucket-local col writes ----
__global__ void k_place2(const int* __restrict__ packed, const int* __restrict__ rp,
                         int* __restrict__ col, int n, int e) {
    __shared__ int cur[BKT];
    int nodeBase = blockIdx.x * BKT;
    int nNodes = min(BKT, n - nodeBase);
    if (threadIdx.x < nNodes) cur[threadIdx.x] = rp[nodeBase + threadIdx.x];
    __syncthreads();
    int start = rp[nodeBase];
    int end = (nodeBase + BKT < n) ? rp[nodeBase + BKT] : e;
    for (int i = start + threadIdx.x; i < end; i += blockDim.x) {
        int u = packed[i];
        int p = atomicAdd(&cur[u & (BKT - 1)], 1);
        col[p] = u >> 7;
    }
}

// ---- h0 = x @ W1  (K=3) ----
__global__ void k_xw1(const float* __restrict__ x, const float* __restrict__ W1,
                      float* __restrict__ h0, int n) {
    int i = blockIdx.x * blockDim.x + threadIdx.x;
    if (i >= n * F) return;
    int node = i >> 5, f = i & (F - 1);
    float x0 = x[node * 3 + 0], x1 = x[node * 3 + 1], x2 = x[node * 3 + 2];
    h0[i] = x0 * W1[f] + x1 * W1[F + f] + x2 * W1[2 * F + f];
}

// ---- g = h @ W2  (32x32) ----
__global__ void k_gemm2(const float* __restrict__ h, const float* __restrict__ W2,
                        float* __restrict__ g, int n) {
    int i = blockIdx.x * blockDim.x + threadIdx.x;
    if (i >= n * F) return;
    int node = i >> 5, f = i & (F - 1);
    const float* row = h + node * F;
    float acc = 0.0f;
#pragma unroll
    for (int k = 0; k < F; ++k) acc += row[k] * W2[k * F + f];
    g[i] = acc;
}

// ---- fused gather conv + bias + relu + pool; 8 threads/node, x4 unroll ----
// rp is exclusive-start form; row range = [rp[node], node+1<n ? rp[node+1] : e)
__global__ void k_gather(const float* __restrict__ hin, const int* __restrict__ rp,
                         const int* __restrict__ col, const float* __restrict__ dinv,
                         const float* __restrict__ bias, const int* __restrict__ batch,
                         float* __restrict__ hout,
                         float* __restrict__ psum, float* __restrict__ pmax,
                         float* __restrict__ cnt, int n, int ne, int store, int do_cnt) {
    int t = blockIdx.x * blockDim.x + threadIdx.x;
    int node = t >> 3, q = t & 7;
    if (node >= n) return;
    int start = rp[node];
    int end = (node + 1 < n) ? rp[node + 1] : ne;
    float dv = dinv[node];

    float4 acc = *reinterpret_cast<const float4*>(hin + node * F + q * 4);
    float dvv = dv * dv;
    acc.x *= dvv; acc.y *= dvv; acc.z *= dvv; acc.w *= dvv;

    int e = start;
    for (; e + 4 <= end; e += 4) {
        int s0 = col[e + 0], s1 = col[e + 1], s2 = col[e + 2], s3 = col[e + 3];
        float w0 = dinv[s0] * dv, w1 = dinv[s1] * dv,
              w2 = dinv[s2] * dv, w3 = dinv[s3] * dv;
        float4 v0 = *reinterpret_cast<const float4*>(hin + s0 * F + q * 4);
        float4 v1 = *reinterpret_cast<const float4*>(hin + s1 * F + q * 4);
        float4 v2 = *reinterpret_cast<const float4*>(hin + s2 * F + q * 4);
        float4 v3 = *reinterpret_cast<const float4*>(hin + s3 * F + q * 4);
        acc.x += v0.x * w0 + v1.x * w1 + v2.x * w2 + v3.x * w3;
        acc.y += v0.y * w0 + v1.y * w1 + v2.y * w2 + v3.y * w3;
        acc.z += v0.z * w0 + v1.z * w1 + v2.z * w2 + v3.z * w3;
        acc.w += v0.w * w0 + v1.w * w1 + v2.w * w2 + v3.w * w3;
    }
    for (; e < end; ++e) {
        int s = col[e];
        float wv = dinv[s] * dv;
        const float4 v = *reinterpret_cast<const float4*>(hin + s * F + q * 4);
        acc.x += v.x * wv; acc.y += v.y * wv; acc.z += v.z * wv; acc.w += v.w * wv;
    }

    const float4 b4 = *reinterpret_cast<const float4*>(bias + q * 4);
    float4 v;
    v.x = fmaxf(acc.x + b4.x, 0.0f);
    v.y = fmaxf(acc.y + b4.y, 0.0f);
    v.z = fmaxf(acc.z + b4.z, 0.0f);
    v.w = fmaxf(acc.w + b4.w, 0.0f);
    if (store) *reinterpret_cast<float4*>(hout + node * F + q * 4) = v;

    int b = batch[node];
    int lane = threadIdx.x & 63;
    int bFirst = __shfl(b, 0);
    int bLast  = __shfl(b, 63);
    if (bFirst == bLast) {
        float4 sv = v, mv = v;
        for (int off = 8; off < 64; off <<= 1) {
            sv.x += __shfl_down(sv.x, off);
            sv.y += __shfl_down(sv.y, off);
            sv.z += __shfl_down(sv.z, off);
            sv.w += __shfl_down(sv.w, off);
            mv.x = fmaxf(mv.x, __shfl_down(mv.x, off));
            mv.y = fmaxf(mv.y, __shfl_down(mv.y, off));
            mv.z = fmaxf(mv.z, __shfl_down(mv.z, off));
            mv.w = fmaxf(mv.w, __shfl_down(mv.w, off));
        }
        if (lane < 8) {
            float* ps = psum + b * F + lane * 4;
            atomicAdd(ps + 0, sv.x);
            atomicAdd(ps + 1, sv.y);
            atomicAdd(ps + 2, sv.z);
            atomicAdd(ps + 3, sv.w);
            int* pm = reinterpret_cast<int*>(pmax + b * F + lane * 4);
            atomicMax(pm + 0, __float_as_int(mv.x));
            atomicMax(pm + 1, __float_as_int(mv.y));
            atomicMax(pm + 2, __float_as_int(mv.z));
            atomicMax(pm + 3, __float_as_int(mv.w));
            if (do_cnt && lane == 0) atomicAdd(&cnt[b], 8.0f);
        }
    } else {
        float* ps = psum + b * F + q * 4;
        atomicAdd(ps + 0, v.x);
        atomicAdd(ps + 1, v.y);
        atomicAdd(ps + 2, v.z);
        atomicAdd(ps + 3, v.w);
        int* pm = reinterpret_cast<int*>(pmax + b * F + q * 4);
        atomicMax(pm + 0, __float_as_int(v.x));
        atomicMax(pm + 1, __float_as_int(v.y));
        atomicMax(pm + 2, __float_as_int(v.z));
        atomicMax(pm + 3, __float_as_int(v.w));
        if (do_cnt && q == 0) atomicAdd(&cnt[b], 1.0f);
    }
}

// ---- fused MLP head: one block per graph (64 threads) ----
__global__ void k_mlp(const float* __restrict__ sum1, const float* __restrict__ max1,
                      const float* __restrict__ sum2, const float* __restrict__ max2,
                      const float* __restrict__ cnt,
                      const float* __restrict__ LW1, const float* __restrict__ Lb1,
                      const float* __restrict__ LW2, const float* __restrict__ Lb2,
                      float* __restrict__ out, int outd) {
    __shared__ float zs[POOLD];
    int b = blockIdx.x, j = threadIdx.x;  // blockDim.x == 64
    float invc = 1.0f / fmaxf(cnt[b], 1.0f);
    float acc = Lb1[j];
#pragma unroll
    for (int i = 0; i < POOLD; ++i) {
        float s;
        if (i < F) s = max1[b * F + i] + max2[b * F + i];
        else       s = (sum1[b * F + i - F] + sum2[b * F + i - F]) * invc;
        acc += s * LW1[i * POOLD + j];
    }
    zs[j] = fmaxf(acc, 0.0f);
    __syncthreads();
    if (j < outd) {
        float a2 = Lb2[j];
#pragma unroll
        for (int jj = 0; jj < POOLD; ++jj) a2 += zs[jj] * LW2[jj * outd + j];
        out[b * outd + j] = a2;
    }
}

extern "C" void kernel_launch(void* const* d_in, const int* in_sizes, int n_in,
                              void* d_out, int out_size, void* d_ws, size_t ws_size,
                              hipStream_t stream) {
    const float* x    = (const float*)d_in[0];
    const int*   ei   = (const int*)d_in[1];
    const int*   batch= (const int*)d_in[2];
    const float* W1   = (const float*)d_in[3];
    const float* b1   = (const float*)d_in[4];
    const float* W2   = (const float*)d_in[5];
    const float* b2   = (const float*)d_in[6];
    const float* LW1  = (const float*)d_in[7];
    const float* Lb1  = (const float*)d_in[8];
    const float* LW2  = (const float*)d_in[9];
    const float* Lb2  = (const float*)d_in[10];
    float* out = (float*)d_out;

    const int N = in_sizes[0] / 3;
    const int E = in_sizes[1] / 2;
    const int OUTD = in_sizes[10];
    const int B = out_size / OUTD;
    const int poolsz = 4 * B * F + B;
    const int NB = (N + BKT - 1) / BKT;   // coarse buckets

    // ---- workspace: [counts][shist][pools] contiguous for one memset ----
    char* p = (char*)d_ws;
    int* counts = (int*)p;            p += (size_t)N * 4;
    int* shist  = (int*)p;            p += (size_t)NB * NSH * 4;
    float* pools= (float*)p;          p += (size_t)poolsz * 4;
    int* rowptr = (int*)p;            p += (size_t)N * 4;
    int* col    = (int*)p;            p += (size_t)E * 4;
    int* partial= (int*)p;            p += 256 * 4;
    int* scur   = (int*)p;            p += (size_t)NB * NSH * 4;
    float* dinv = (float*)p;          p += (size_t)N * 4;
    float* buf0 = (float*)p;          p += (size_t)N * F * 4;
    float* buf1 = (float*)p;          p += (size_t)N * F * 4;
    int* packed = (int*)buf0;         // aliased: consumed before k_xw1 writes buf0
    float* sum1 = pools;
    float* max1 = sum1 + B * F;
    float* sum2 = max1 + B * F;
    float* max2 = sum2 + B * F;
    float* cnt  = max2 + B * F;

    const int BS = 256;
    auto g1 = [&](long long n) { return (int)((n + BS - 1) / BS); };
    const int nScanBlocks = (N + SCAN_CHUNK - 1) / SCAN_CHUNK;
    const int nBinBlocks = (E + EPB - 1) / EPB;

    // CSR build + norms
    hipMemsetAsync(counts, 0, ((size_t)N + (size_t)NB * NSH + poolsz) * 4, stream);
    k_hist<<<g1((E + 3) / 4), BS, 0, stream>>>(ei, counts, shist, E);
    k_scan1<<<nScanBlocks, 256, 0, stream>>>(counts, rowptr, partial, dinv, N);
    k_scan2<<<1, 256, 0, stream>>>(partial, nScanBlocks);
    k_scan3<<<nScanBlocks, 256, 0, stream>>>(rowptr, partial, N);
    k_scur<<<g1(NB), BS, 0, stream>>>(rowptr, shist, scur, NB);
    k_bin<<<nBinBlocks, BS, 0, stream>>>(ei, scur, packed, E);
    k_place2<<<NB, BS, 0, stream>>>(packed, rowptr, col, N, E);

    // layer 1
    k_xw1<<<g1((long long)N * F), BS, 0, stream>>>(x, W1, buf0, N);
    k_gather<<<g1((long long)N * 8), BS, 0, stream>>>(buf0, rowptr, col, dinv, b1,
                                                      batch, buf1, sum1, max1, cnt,
                                                      N, E, /*store=*/1, /*do_cnt=*/1);
    // layer 2
    k_gemm2<<<g1((long long)N * F), BS, 0, stream>>>(buf1, W2, buf0, N);
    k_gather<<<g1((long long)N * 8), BS, 0, stream>>>(buf0, rowptr, col, dinv, b2,
                                                      batch, buf1, sum2, max2, cnt,
                                                      N, E, /*store=*/0, /*do_cnt=*/0);

    // MLP head
    k_mlp<<<B, 64, 0, stream>>>(sum1, max1, sum2, max2, cnt,
                                LW1, Lb1, LW2, Lb2, out, OUTD);
}

// Round 6
// 548.605 us; speedup vs baseline: 2.2661x; 1.3420x over previous
//
#include <hip/hip_runtime.h>

// Topology encoder: 2-layer GCN (N=100k nodes, E=3.2M edges) + max/mean pool
// over B=64 graphs + 2-layer MLP. All fp32.
//
// CSR-by-dst built per call with NO per-edge global atomics on the node axis:
//   k_histB : LDS-privatized coarse-bucket histogram (shard = block group)
//   k_bscan : single-block scan of bucket totals -> bstart + sharded cursors
//   k_bin   : partition edges into bucket regions (packed (src<<7)|dstlow)
//   k_place2: per-bucket LDS degree count + scan -> rowptr, dinv, col
// Layers are gathers (no fp32 atomics). Pool atomics wave-reduced.

#define F 32
#define POOLD 64
#define BKT 128           // nodes per coarse bucket (log2 = 7)
#define NSH 8             // cursor shards per bucket (== XCD round-robin)
#define EPB 4096          // edges per k_histB/k_bin block (log2 = 12)
#define MAXBUCK 1024      // supports N <= 131072

// ---- LDS-privatized bucket histogram; flush to shist[bucket][shard] ----
__global__ void k_histB(const int* __restrict__ ei, int* __restrict__ shist,
                        int e, int nbuck) {
    __shared__ int h[MAXBUCK];
    for (int t = threadIdx.x; t < nbuck; t += 256) h[t] = 0;
    __syncthreads();
    int base = blockIdx.x * EPB;
#pragma unroll
    for (int k = 0; k < 4; ++k) {
        int i = base + (k * 256 + threadIdx.x) * 4;
        if (i + 4 <= e) {
            int4 d4 = *reinterpret_cast<const int4*>(ei + e + i);
            atomicAdd(&h[d4.x >> 7], 1);
            atomicAdd(&h[d4.y >> 7], 1);
            atomicAdd(&h[d4.z >> 7], 1);
            atomicAdd(&h[d4.w >> 7], 1);
        } else {
            for (int j = i; j < e && j < i + 4; ++j)
                atomicAdd(&h[ei[e + j] >> 7], 1);
        }
    }
    __syncthreads();
    int sh = blockIdx.x & (NSH - 1);
    for (int b = threadIdx.x; b < nbuck; b += 256)
        if (h[b]) atomicAdd(&shist[b * NSH + sh], h[b]);
}

// ---- single block: scan bucket totals -> bstart; per-shard cursors scur ----
__global__ void k_bscan(const int* __restrict__ shist, int* __restrict__ bstart,
                        int* __restrict__ scur, int nbuck, int e) {
    __shared__ int lds[256];
    int t = threadIdx.x;
    int T[4];
    int s = 0;
#pragma unroll
    for (int j = 0; j < 4; ++j) {
        int b = t * 4 + j;
        int v = 0;
        if (b < nbuck)
            for (int k = 0; k < NSH; ++k) v += shist[b * NSH + k];
        T[j] = v; s += v;
    }
    lds[t] = s;
    __syncthreads();
    int val = s;
    for (int off = 1; off < 256; off <<= 1) {
        int other = (t >= off) ? lds[t - off] : 0;
        __syncthreads();
        val += other;
        lds[t] = val;
        __syncthreads();
    }
    int excl = val - s;
#pragma unroll
    for (int j = 0; j < 4; ++j) {
        int b = t * 4 + j;
        if (b < nbuck) {
            bstart[b] = excl;
            int acc = excl;
            for (int k = 0; k < NSH; ++k) {
                scur[b * NSH + k] = acc;
                acc += shist[b * NSH + k];
            }
            excl += T[j];
        }
    }
    if (t == 0) bstart[nbuck] = e;
}

// ---- partition edges; cursor shard = block group (XCD round-robin) ----
__global__ void k_bin(const int* __restrict__ ei, int* __restrict__ scur,
                      int* __restrict__ packed, int e) {
    int sh = blockIdx.x & (NSH - 1);
    int base = blockIdx.x * EPB;
#pragma unroll
    for (int k = 0; k < 4; ++k) {
        int i = base + (k * 256 + threadIdx.x) * 4;
        if (i + 4 <= e) {
            int4 s4 = *reinterpret_cast<const int4*>(ei + i);
            int4 d4 = *reinterpret_cast<const int4*>(ei + e + i);
            int p0 = atomicAdd(&scur[((d4.x >> 7) << 3) | sh], 1);
            int p1 = atomicAdd(&scur[((d4.y >> 7) << 3) | sh], 1);
            int p2 = atomicAdd(&scur[((d4.z >> 7) << 3) | sh], 1);
            int p3 = atomicAdd(&scur[((d4.w >> 7) << 3) | sh], 1);
            packed[p0] = (s4.x << 7) | (d4.x & (BKT - 1));
            packed[p1] = (s4.y << 7) | (d4.y & (BKT - 1));
            packed[p2] = (s4.z << 7) | (d4.z & (BKT - 1));
            packed[p3] = (s4.w << 7) | (d4.w & (BKT - 1));
        } else {
            for (int j = i; j < e && j < i + 4; ++j) {
                int s = ei[j], d = ei[e + j];
                int p = atomicAdd(&scur[((d >> 7) << 3) | sh], 1);
                packed[p] = (s << 7) | (d & (BKT - 1));
            }
        }
    }
}

// ---- per bucket: LDS degree count + scan -> rowptr/dinv/cursors; place col ----
__global__ void k_place2(const int* __restrict__ packed, const int* __restrict__ bstart,
                         int* __restrict__ col, int* __restrict__ rp,
                         float* __restrict__ dinv, int n) {
    __shared__ int deg[BKT];
    __shared__ int cur[BKT];
    __shared__ int sc[BKT];
    int nodeBase = blockIdx.x * BKT;
    int nNodes = min(BKT, n - nodeBase);
    int t = threadIdx.x;
    if (t < BKT) deg[t] = 0;
    __syncthreads();
    int start = bstart[blockIdx.x];
    int end = bstart[blockIdx.x + 1];
    for (int i = start + t; i < end; i += blockDim.x)
        atomicAdd(&deg[packed[i] & (BKT - 1)], 1);
    __syncthreads();
    int d0 = (t < BKT) ? deg[t] : 0;
    if (t < BKT) sc[t] = d0;
    __syncthreads();
    int val = d0;
    for (int off = 1; off < BKT; off <<= 1) {
        int other = (t < BKT && t >= off) ? sc[t - off] : 0;
        __syncthreads();
        if (t < BKT) { val += other; sc[t] = val; }
        __syncthreads();
    }
    if (t < nNodes) {
        int ex = start + val - d0;   // bucket start + exclusive prefix
        rp[nodeBase + t] = ex;
        cur[t] = ex;
        dinv[nodeBase + t] = rsqrtf((float)d0 + 1.0f);
    }
    __syncthreads();
    for (int i = start + t; i < end; i += blockDim.x) {
        int u = packed[i];
        int p = atomicAdd(&cur[u & (BKT - 1)], 1);
        col[p] = u >> 7;
    }
}

// ---- h0 = x @ W1  (K=3) ----
__global__ void k_xw1(const float* __restrict__ x, const float* __restrict__ W1,
                      float* __restrict__ h0, int n) {
    int i = blockIdx.x * blockDim.x + threadIdx.x;
    if (i >= n * F) return;
    int node = i >> 5, f = i & (F - 1);
    float x0 = x[node * 3 + 0], x1 = x[node * 3 + 1], x2 = x[node * 3 + 2];
    h0[i] = x0 * W1[f] + x1 * W1[F + f] + x2 * W1[2 * F + f];
}

// ---- g = h @ W2  (32x32) ----
__global__ void k_gemm2(const float* __restrict__ h, const float* __restrict__ W2,
                        float* __restrict__ g, int n) {
    int i = blockIdx.x * blockDim.x + threadIdx.x;
    if (i >= n * F) return;
    int node = i >> 5, f = i & (F - 1);
    const float* row = h + node * F;
    float acc = 0.0f;
#pragma unroll
    for (int k = 0; k < F; ++k) acc += row[k] * W2[k * F + f];
    g[i] = acc;
}

// ---- fused gather conv + bias + relu + pool; 8 threads/node, x4 unroll ----
__global__ void k_gather(const float* __restrict__ hin, const int* __restrict__ rp,
                         const int* __restrict__ col, const float* __restrict__ dinv,
                         const float* __restrict__ bias, const int* __restrict__ batch,
                         float* __restrict__ hout,
                         float* __restrict__ psum, float* __restrict__ pmax,
                         float* __restrict__ cnt, int n, int ne, int store, int do_cnt) {
    int t = blockIdx.x * blockDim.x + threadIdx.x;
    int node = t >> 3, q = t & 7;
    if (node >= n) return;
    int start = rp[node];
    int end = (node + 1 < n) ? rp[node + 1] : ne;
    float dv = dinv[node];

    float4 acc = *reinterpret_cast<const float4*>(hin + node * F + q * 4);
    float dvv = dv * dv;
    acc.x *= dvv; acc.y *= dvv; acc.z *= dvv; acc.w *= dvv;

    int e = start;
    for (; e + 4 <= end; e += 4) {
        int s0 = col[e + 0], s1 = col[e + 1], s2 = col[e + 2], s3 = col[e + 3];
        float w0 = dinv[s0] * dv, w1 = dinv[s1] * dv,
              w2 = dinv[s2] * dv, w3 = dinv[s3] * dv;
        float4 v0 = *reinterpret_cast<const float4*>(hin + s0 * F + q * 4);
        float4 v1 = *reinterpret_cast<const float4*>(hin + s1 * F + q * 4);
        float4 v2 = *reinterpret_cast<const float4*>(hin + s2 * F + q * 4);
        float4 v3 = *reinterpret_cast<const float4*>(hin + s3 * F + q * 4);
        acc.x += v0.x * w0 + v1.x * w1 + v2.x * w2 + v3.x * w3;
        acc.y += v0.y * w0 + v1.y * w1 + v2.y * w2 + v3.y * w3;
        acc.z += v0.z * w0 + v1.z * w1 + v2.z * w2 + v3.z * w3;
        acc.w += v0.w * w0 + v1.w * w1 + v2.w * w2 + v3.w * w3;
    }
    for (; e < end; ++e) {
        int s = col[e];
        float wv = dinv[s] * dv;
        const float4 v = *reinterpret_cast<const float4*>(hin + s * F + q * 4);
        acc.x += v.x * wv; acc.y += v.y * wv; acc.z += v.z * wv; acc.w += v.w * wv;
    }

    const float4 b4 = *reinterpret_cast<const float4*>(bias + q * 4);
    float4 v;
    v.x = fmaxf(acc.x + b4.x, 0.0f);
    v.y = fmaxf(acc.y + b4.y, 0.0f);
    v.z = fmaxf(acc.z + b4.z, 0.0f);
    v.w = fmaxf(acc.w + b4.w, 0.0f);
    if (store) *reinterpret_cast<float4*>(hout + node * F + q * 4) = v;

    int b = batch[node];
    int lane = threadIdx.x & 63;
    int bFirst = __shfl(b, 0);
    int bLast  = __shfl(b, 63);
    if (bFirst == bLast) {
        float4 sv = v, mv = v;
        for (int off = 8; off < 64; off <<= 1) {
            sv.x += __shfl_down(sv.x, off);
            sv.y += __shfl_down(sv.y, off);
            sv.z += __shfl_down(sv.z, off);
            sv.w += __shfl_down(sv.w, off);
            mv.x = fmaxf(mv.x, __shfl_down(mv.x, off));
            mv.y = fmaxf(mv.y, __shfl_down(mv.y, off));
            mv.z = fmaxf(mv.z, __shfl_down(mv.z, off));
            mv.w = fmaxf(mv.w, __shfl_down(mv.w, off));
        }
        if (lane < 8) {
            float* ps = psum + b * F + lane * 4;
            atomicAdd(ps + 0, sv.x);
            atomicAdd(ps + 1, sv.y);
            atomicAdd(ps + 2, sv.z);
            atomicAdd(ps + 3, sv.w);
            int* pm = reinterpret_cast<int*>(pmax + b * F + lane * 4);
            atomicMax(pm + 0, __float_as_int(mv.x));
            atomicMax(pm + 1, __float_as_int(mv.y));
            atomicMax(pm + 2, __float_as_int(mv.z));
            atomicMax(pm + 3, __float_as_int(mv.w));
            if (do_cnt && lane == 0) atomicAdd(&cnt[b], 8.0f);
        }
    } else {
        float* ps = psum + b * F + q * 4;
        atomicAdd(ps + 0, v.x);
        atomicAdd(ps + 1, v.y);
        atomicAdd(ps + 2, v.z);
        atomicAdd(ps + 3, v.w);
        int* pm = reinterpret_cast<int*>(pmax + b * F + q * 4);
        atomicMax(pm + 0, __float_as_int(v.x));
        atomicMax(pm + 1, __float_as_int(v.y));
        atomicMax(pm + 2, __float_as_int(v.z));
        atomicMax(pm + 3, __float_as_int(v.w));
        if (do_cnt && q == 0) atomicAdd(&cnt[b], 1.0f);
    }
}

// ---- fused MLP head: one block per graph (64 threads) ----
__global__ void k_mlp(const float* __restrict__ sum1, const float* __restrict__ max1,
                      const float* __restrict__ sum2, const float* __restrict__ max2,
                      const float* __restrict__ cnt,
                      const float* __restrict__ LW1, const float* __restrict__ Lb1,
                      const float* __restrict__ LW2, const float* __restrict__ Lb2,
                      float* __restrict__ out, int outd) {
    __shared__ float zs[POOLD];
    int b = blockIdx.x, j = threadIdx.x;  // blockDim.x == 64
    float invc = 1.0f / fmaxf(cnt[b], 1.0f);
    float acc = Lb1[j];
#pragma unroll
    for (int i = 0; i < POOLD; ++i) {
        float s;
        if (i < F) s = max1[b * F + i] + max2[b * F + i];
        else       s = (sum1[b * F + i - F] + sum2[b * F + i - F]) * invc;
        acc += s * LW1[i * POOLD + j];
    }
    zs[j] = fmaxf(acc, 0.0f);
    __syncthreads();
    if (j < outd) {
        float a2 = Lb2[j];
#pragma unroll
        for (int jj = 0; jj < POOLD; ++jj) a2 += zs[jj] * LW2[jj * outd + j];
        out[b * outd + j] = a2;
    }
}

extern "C" void kernel_launch(void* const* d_in, const int* in_sizes, int n_in,
                              void* d_out, int out_size, void* d_ws, size_t ws_size,
                              hipStream_t stream) {
    const float* x    = (const float*)d_in[0];
    const int*   ei   = (const int*)d_in[1];
    const int*   batch= (const int*)d_in[2];
    const float* W1   = (const float*)d_in[3];
    const float* b1   = (const float*)d_in[4];
    const float* W2   = (const float*)d_in[5];
    const float* b2   = (const float*)d_in[6];
    const float* LW1  = (const float*)d_in[7];
    const float* Lb1  = (const float*)d_in[8];
    const float* LW2  = (const float*)d_in[9];
    const float* Lb2  = (const float*)d_in[10];
    float* out = (float*)d_out;

    const int N = in_sizes[0] / 3;
    const int E = in_sizes[1] / 2;
    const int OUTD = in_sizes[10];
    const int B = out_size / OUTD;
    const int poolsz = 4 * B * F + B;
    const int NB = (N + BKT - 1) / BKT;   // coarse buckets (<= MAXBUCK)

    // ---- workspace: [shist][pools] contiguous for one memset ----
    char* p = (char*)d_ws;
    int* shist  = (int*)p;            p += (size_t)NB * NSH * 4;
    float* pools= (float*)p;          p += (size_t)poolsz * 4;
    int* bstart = (int*)p;            p += (size_t)(NB + 1) * 4;
    int* scur   = (int*)p;            p += (size_t)NB * NSH * 4;
    int* rowptr = (int*)p;            p += (size_t)N * 4;
    int* col    = (int*)p;            p += (size_t)E * 4;
    float* dinv = (float*)p;          p += (size_t)N * 4;
    float* buf0 = (float*)p;          p += (size_t)N * F * 4;
    float* buf1 = (float*)p;          p += (size_t)N * F * 4;
    int* packed = (int*)buf0;         // aliased: consumed before k_xw1 writes buf0
    float* sum1 = pools;
    float* max1 = sum1 + B * F;
    float* sum2 = max1 + B * F;
    float* max2 = sum2 + B * F;
    float* cnt  = max2 + B * F;

    const int BS = 256;
    auto g1 = [&](long long n) { return (int)((n + BS - 1) / BS); };
    const int nBinBlocks = (E + EPB - 1) / EPB;

    // CSR build + norms (no per-edge global atomics on the node axis)
    hipMemsetAsync(shist, 0, ((size_t)NB * NSH + poolsz) * 4, stream);
    k_histB<<<nBinBlocks, BS, 0, stream>>>(ei, shist, E, NB);
    k_bscan<<<1, 256, 0, stream>>>(shist, bstart, scur, NB, E);
    k_bin<<<nBinBlocks, BS, 0, stream>>>(ei, scur, packed, E);
    k_place2<<<NB, BS, 0, stream>>>(packed, bstart, col, rowptr, dinv, N);

    // layer 1
    k_xw1<<<g1((long long)N * F), BS, 0, stream>>>(x, W1, buf0, N);
    k_gather<<<g1((long long)N * 8), BS, 0, stream>>>(buf0, rowptr, col, dinv, b1,
                                                      batch, buf1, sum1, max1, cnt,
                                                      N, E, /*store=*/1, /*do_cnt=*/1);
    // layer 2
    k_gemm2<<<g1((long long)N * F), BS, 0, stream>>>(buf1, W2, buf0, N);
    k_gather<<<g1((long long)N * 8), BS, 0, stream>>>(buf0, rowptr, col, dinv, b2,
                                                      batch, buf1, sum2, max2, cnt,
                                                      N, E, /*store=*/0, /*do_cnt=*/0);

    // MLP head
    k_mlp<<<B, 64, 0, stream>>>(sum1, max1, sum2, max2, cnt,
                                LW1, Lb1, LW2, Lb2, out, OUTD);
}

// Round 7
// 482.109 us; speedup vs baseline: 2.5786x; 1.1379x over previous
//
#include <hip/hip_runtime.h>
#include <hip/hip_fp16.h>

// Topology encoder: 2-layer GCN (N=100k nodes, E=3.2M edges) + max/mean pool
// over B=64 graphs + 2-layer MLP. fp32 inputs/outputs; node features stored
// fp16 (64B rows = 1 cache line) with fp32 accumulation.
//
// CSR-by-dst built per call with no per-edge global atomics on the node axis:
//   k_histB : LDS-privatized coarse-bucket histogram (shard = block group)
//   k_bscan : single-block scan of bucket totals -> bstart + sharded cursors
//   k_bin   : partition edges into bucket regions (packed (src<<7)|dstlow)
//   k_place2: per-bucket LDS degree count + scan -> rowptr, dinv, col
// Layers are gathers (no fp32 scatter atomics). Pool atomics wave-reduced.

#define F 32
#define POOLD 64
#define BKT 128           // nodes per coarse bucket (log2 = 7)
#define NSH 8             // cursor shards per bucket (== XCD round-robin)
#define EPB 4096          // edges per k_histB/k_bin block (log2 = 12)
#define MAXBUCK 1024      // supports N <= 131072

typedef __attribute__((ext_vector_type(8))) _Float16 half8;

// ---- LDS-privatized bucket histogram; flush to shist[bucket][shard] ----
__global__ void k_histB(const int* __restrict__ ei, int* __restrict__ shist,
                        int e, int nbuck) {
    __shared__ int h[MAXBUCK];
    for (int t = threadIdx.x; t < nbuck; t += 256) h[t] = 0;
    __syncthreads();
    int base = blockIdx.x * EPB;
#pragma unroll
    for (int k = 0; k < 4; ++k) {
        int i = base + (k * 256 + threadIdx.x) * 4;
        if (i + 4 <= e) {
            int4 d4 = *reinterpret_cast<const int4*>(ei + e + i);
            atomicAdd(&h[d4.x >> 7], 1);
            atomicAdd(&h[d4.y >> 7], 1);
            atomicAdd(&h[d4.z >> 7], 1);
            atomicAdd(&h[d4.w >> 7], 1);
        } else {
            for (int j = i; j < e && j < i + 4; ++j)
                atomicAdd(&h[ei[e + j] >> 7], 1);
        }
    }
    __syncthreads();
    int sh = blockIdx.x & (NSH - 1);
    for (int b = threadIdx.x; b < nbuck; b += 256)
        if (h[b]) atomicAdd(&shist[b * NSH + sh], h[b]);
}

// ---- single block: scan bucket totals -> bstart; per-shard cursors scur ----
__global__ void k_bscan(const int* __restrict__ shist, int* __restrict__ bstart,
                        int* __restrict__ scur, int nbuck, int e) {
    __shared__ int lds[256];
    int t = threadIdx.x;
    int T[4];
    int s = 0;
#pragma unroll
    for (int j = 0; j < 4; ++j) {
        int b = t * 4 + j;
        int v = 0;
        if (b < nbuck)
            for (int k = 0; k < NSH; ++k) v += shist[b * NSH + k];
        T[j] = v; s += v;
    }
    lds[t] = s;
    __syncthreads();
    int val = s;
    for (int off = 1; off < 256; off <<= 1) {
        int other = (t >= off) ? lds[t - off] : 0;
        __syncthreads();
        val += other;
        lds[t] = val;
        __syncthreads();
    }
    int excl = val - s;
#pragma unroll
    for (int j = 0; j < 4; ++j) {
        int b = t * 4 + j;
        if (b < nbuck) {
            bstart[b] = excl;
            int acc = excl;
            for (int k = 0; k < NSH; ++k) {
                scur[b * NSH + k] = acc;
                acc += shist[b * NSH + k];
            }
            excl += T[j];
        }
    }
    if (t == 0) bstart[nbuck] = e;
}

// ---- partition edges; 16 batched atomics/stores; shard = block group ----
__global__ void k_bin(const int* __restrict__ ei, int* __restrict__ scur,
                      int* __restrict__ packed, int e) {
    int sh = blockIdx.x & (NSH - 1);
    int base = blockIdx.x * EPB;
    int4 s4[4], d4[4];
    bool full[4];
#pragma unroll
    for (int k = 0; k < 4; ++k) {
        int i = base + (k * 256 + threadIdx.x) * 4;
        full[k] = (i + 4 <= e);
        if (full[k]) {
            s4[k] = *reinterpret_cast<const int4*>(ei + i);
            d4[k] = *reinterpret_cast<const int4*>(ei + e + i);
        }
    }
    int p[16];
#pragma unroll
    for (int k = 0; k < 4; ++k) {
        if (full[k]) {
            p[4 * k + 0] = atomicAdd(&scur[((d4[k].x >> 7) << 3) | sh], 1);
            p[4 * k + 1] = atomicAdd(&scur[((d4[k].y >> 7) << 3) | sh], 1);
            p[4 * k + 2] = atomicAdd(&scur[((d4[k].z >> 7) << 3) | sh], 1);
            p[4 * k + 3] = atomicAdd(&scur[((d4[k].w >> 7) << 3) | sh], 1);
        }
    }
#pragma unroll
    for (int k = 0; k < 4; ++k) {
        if (full[k]) {
            packed[p[4 * k + 0]] = (s4[k].x << 7) | (d4[k].x & (BKT - 1));
            packed[p[4 * k + 1]] = (s4[k].y << 7) | (d4[k].y & (BKT - 1));
            packed[p[4 * k + 2]] = (s4[k].z << 7) | (d4[k].z & (BKT - 1));
            packed[p[4 * k + 3]] = (s4[k].w << 7) | (d4[k].w & (BKT - 1));
        } else {
            int i = base + (k * 256 + threadIdx.x) * 4;
            for (int j = i; j < e && j < i + 4; ++j) {
                int s = ei[j], d = ei[e + j];
                int q = atomicAdd(&scur[((d >> 7) << 3) | sh], 1);
                packed[q] = (s << 7) | (d & (BKT - 1));
            }
        }
    }
}

// ---- per bucket: LDS degree count + scan -> rowptr/dinv/cursors; place col ----
__global__ void k_place2(const int* __restrict__ packed, const int* __restrict__ bstart,
                         int* __restrict__ col, int* __restrict__ rp,
                         float* __restrict__ dinv, int n) {
    __shared__ int deg[BKT];
    __shared__ int cur[BKT];
    __shared__ int sc[BKT];
    int nodeBase = blockIdx.x * BKT;
    int nNodes = min(BKT, n - nodeBase);
    int t = threadIdx.x;
    if (t < BKT) deg[t] = 0;
    __syncthreads();
    int start = bstart[blockIdx.x];
    int end = bstart[blockIdx.x + 1];
    for (int i = start + t; i < end; i += blockDim.x)
        atomicAdd(&deg[packed[i] & (BKT - 1)], 1);
    __syncthreads();
    int d0 = (t < BKT) ? deg[t] : 0;
    if (t < BKT) sc[t] = d0;
    __syncthreads();
    int val = d0;
    for (int off = 1; off < BKT; off <<= 1) {
        int other = (t < BKT && t >= off) ? sc[t - off] : 0;
        __syncthreads();
        if (t < BKT) { val += other; sc[t] = val; }
        __syncthreads();
    }
    if (t < nNodes) {
        int ex = start + val - d0;   // bucket start + exclusive prefix
        rp[nodeBase + t] = ex;
        cur[t] = ex;
        dinv[nodeBase + t] = rsqrtf((float)d0 + 1.0f);
    }
    __syncthreads();
    for (int i = start + t; i < end; i += blockDim.x) {
        int u = packed[i];
        int p = atomicAdd(&cur[u & (BKT - 1)], 1);
        col[p] = u >> 7;
    }
}

// ---- h0 = x @ W1  (K=3), fp16 out ----
__global__ void k_xw1(const float* __restrict__ x, const float* __restrict__ W1,
                      _Float16* __restrict__ h0, int n) {
    int i = blockIdx.x * blockDim.x + threadIdx.x;
    if (i >= n * F) return;
    int node = i >> 5, f = i & (F - 1);
    float x0 = x[node * 3 + 0], x1 = x[node * 3 + 1], x2 = x[node * 3 + 2];
    h0[i] = (_Float16)(x0 * W1[f] + x1 * W1[F + f] + x2 * W1[2 * F + f]);
}

// ---- g = h @ W2  (32x32), fp16 in/out, fp32 accumulate ----
__global__ void k_gemm2(const _Float16* __restrict__ h, const float* __restrict__ W2,
                        _Float16* __restrict__ g, int n) {
    int i = blockIdx.x * blockDim.x + threadIdx.x;
    if (i >= n * F) return;
    int node = i >> 5, f = i & (F - 1);
    const _Float16* row = h + (size_t)node * F;
    float acc = 0.0f;
#pragma unroll
    for (int k = 0; k < F; ++k) acc += (float)row[k] * W2[k * F + f];
    g[i] = (_Float16)acc;
}

// ---- fused gather conv + bias + relu + pool; 4 threads/node (8 feats each) ----
// rp exclusive-start; row range = [rp[node], node+1<n ? rp[node+1] : ne)
__global__ void k_gather(const _Float16* __restrict__ hin, const int* __restrict__ rp,
                         const int* __restrict__ col, const float* __restrict__ dinv,
                         const float* __restrict__ bias, const int* __restrict__ batch,
                         _Float16* __restrict__ hout,
                         float* __restrict__ psum, float* __restrict__ pmax,
                         float* __restrict__ cnt, int n, int ne, int store, int do_cnt) {
    int t = blockIdx.x * blockDim.x + threadIdx.x;
    int node = t >> 2, q = t & 3;
    if (node >= n) return;
    int start = rp[node];
    int end = (node + 1 < n) ? rp[node + 1] : ne;
    float dv = dinv[node];

    half8 hv = *reinterpret_cast<const half8*>(hin + (size_t)node * F + q * 8);
    float dvv = dv * dv;
    float acc[8];
#pragma unroll
    for (int j = 0; j < 8; ++j) acc[j] = (float)hv[j] * dvv;

    int e = start;
    for (; e + 4 <= end; e += 4) {
        int s0 = col[e + 0], s1 = col[e + 1], s2 = col[e + 2], s3 = col[e + 3];
        float w0 = dinv[s0] * dv, w1 = dinv[s1] * dv,
              w2 = dinv[s2] * dv, w3 = dinv[s3] * dv;
        half8 v0 = *reinterpret_cast<const half8*>(hin + (size_t)s0 * F + q * 8);
        half8 v1 = *reinterpret_cast<const half8*>(hin + (size_t)s1 * F + q * 8);
        half8 v2 = *reinterpret_cast<const half8*>(hin + (size_t)s2 * F + q * 8);
        half8 v3 = *reinterpret_cast<const half8*>(hin + (size_t)s3 * F + q * 8);
#pragma unroll
        for (int j = 0; j < 8; ++j)
            acc[j] += (float)v0[j] * w0 + (float)v1[j] * w1 +
                      (float)v2[j] * w2 + (float)v3[j] * w3;
    }
    for (; e < end; ++e) {
        int s = col[e];
        float wv = dinv[s] * dv;
        half8 v = *reinterpret_cast<const half8*>(hin + (size_t)s * F + q * 8);
#pragma unroll
        for (int j = 0; j < 8; ++j) acc[j] += (float)v[j] * wv;
    }

    float vv[8];
#pragma unroll
    for (int j = 0; j < 8; ++j) vv[j] = fmaxf(acc[j] + bias[q * 8 + j], 0.0f);
    if (store) {
        half8 o;
#pragma unroll
        for (int j = 0; j < 8; ++j) o[j] = (_Float16)vv[j];
        *reinterpret_cast<half8*>(hout + (size_t)node * F + q * 8) = o;
    }

    int b = batch[node];
    int lane = threadIdx.x & 63;
    int bFirst = __shfl(b, 0);
    int bLast  = __shfl(b, 63);
    if (bFirst == bLast) {
        // all 16 nodes of this wave in one graph: stride-4 tree reduce
        float sv[8], mv[8];
#pragma unroll
        for (int j = 0; j < 8; ++j) { sv[j] = vv[j]; mv[j] = vv[j]; }
        for (int off = 4; off < 64; off <<= 1) {
#pragma unroll
            for (int j = 0; j < 8; ++j) {
                sv[j] += __shfl_down(sv[j], off);
                mv[j] = fmaxf(mv[j], __shfl_down(mv[j], off));
            }
        }
        if (lane < 4) {
            float* ps = psum + b * F + lane * 8;
            int* pm = reinterpret_cast<int*>(pmax + b * F + lane * 8);
#pragma unroll
            for (int j = 0; j < 8; ++j) {
                atomicAdd(ps + j, sv[j]);
                atomicMax(pm + j, __float_as_int(mv[j]));  // vv >= 0
            }
            if (do_cnt && lane == 0) atomicAdd(&cnt[b], 16.0f);
        }
    } else {
        float* ps = psum + b * F + q * 8;
        int* pm = reinterpret_cast<int*>(pmax + b * F + q * 8);
#pragma unroll
        for (int j = 0; j < 8; ++j) {
            atomicAdd(ps + j, vv[j]);
            atomicMax(pm + j, __float_as_int(vv[j]));
        }
        if (do_cnt && q == 0) atomicAdd(&cnt[b], 1.0f);
    }
}

// ---- fused MLP head: one block per graph (64 threads) ----
__global__ void k_mlp(const float* __restrict__ sum1, const float* __restrict__ max1,
                      const float* __restrict__ sum2, const float* __restrict__ max2,
                      const float* __restrict__ cnt,
                      const float* __restrict__ LW1, const float* __restrict__ Lb1,
                      const float* __restrict__ LW2, const float* __restrict__ Lb2,
                      float* __restrict__ out, int outd) {
    __shared__ float zs[POOLD];
    int b = blockIdx.x, j = threadIdx.x;  // blockDim.x == 64
    float invc = 1.0f / fmaxf(cnt[b], 1.0f);
    float acc = Lb1[j];
#pragma unroll
    for (int i = 0; i < POOLD; ++i) {
        float s;
        if (i < F) s = max1[b * F + i] + max2[b * F + i];
        else       s = (sum1[b * F + i - F] + sum2[b * F + i - F]) * invc;
        acc += s * LW1[i * POOLD + j];
    }
    zs[j] = fmaxf(acc, 0.0f);
    __syncthreads();
    if (j < outd) {
        float a2 = Lb2[j];
#pragma unroll
        for (int jj = 0; jj < POOLD; ++jj) a2 += zs[jj] * LW2[jj * outd + j];
        out[b * outd + j] = a2;
    }
}

extern "C" void kernel_launch(void* const* d_in, const int* in_sizes, int n_in,
                              void* d_out, int out_size, void* d_ws, size_t ws_size,
                              hipStream_t stream) {
    const float* x    = (const float*)d_in[0];
    const int*   ei   = (const int*)d_in[1];
    const int*   batch= (const int*)d_in[2];
    const float* W1   = (const float*)d_in[3];
    const float* b1   = (const float*)d_in[4];
    const float* W2   = (const float*)d_in[5];
    const float* b2   = (const float*)d_in[6];
    const float* LW1  = (const float*)d_in[7];
    const float* Lb1  = (const float*)d_in[8];
    const float* LW2  = (const float*)d_in[9];
    const float* Lb2  = (const float*)d_in[10];
    float* out = (float*)d_out;

    const int N = in_sizes[0] / 3;
    const int E = in_sizes[1] / 2;
    const int OUTD = in_sizes[10];
    const int B = out_size / OUTD;
    const int poolsz = 4 * B * F + B;
    const int NB = (N + BKT - 1) / BKT;   // coarse buckets (<= MAXBUCK)

    // ---- workspace: [shist][pools] contiguous for one memset ----
    char* p = (char*)d_ws;
    int* shist  = (int*)p;            p += (size_t)NB * NSH * 4;
    float* pools= (float*)p;          p += (size_t)poolsz * 4;
    int* bstart = (int*)p;            p += (size_t)(NB + 1) * 4;
    int* scur   = (int*)p;            p += (size_t)NB * NSH * 4;
    int* rowptr = (int*)p;            p += (size_t)N * 4;
    int* col    = (int*)p;            p += (size_t)E * 4;
    float* dinv = (float*)p;          p += (size_t)N * 4;
    _Float16* buf0 = (_Float16*)p;    p += (size_t)N * F * 2;
    _Float16* buf1 = (_Float16*)p;    p += (size_t)N * F * 2;
    int* packed = (int*)buf0;         // aliased over buf0+buf1 (E*4 == N*F*4 bytes);
                                      // consumed by k_place2 before buf0/buf1 written
    float* sum1 = pools;
    float* max1 = sum1 + B * F;
    float* sum2 = max1 + B * F;
    float* max2 = sum2 + B * F;
    float* cnt  = max2 + B * F;

    const int BS = 256;
    auto g1 = [&](long long n) { return (int)((n + BS - 1) / BS); };
    const int nBinBlocks = (E + EPB - 1) / EPB;

    // CSR build + norms (no per-edge global atomics on the node axis)
    hipMemsetAsync(shist, 0, ((size_t)NB * NSH + poolsz) * 4, stream);
    k_histB<<<nBinBlocks, BS, 0, stream>>>(ei, shist, E, NB);
    k_bscan<<<1, 256, 0, stream>>>(shist, bstart, scur, NB, E);
    k_bin<<<nBinBlocks, BS, 0, stream>>>(ei, scur, packed, E);
    k_place2<<<NB, BS, 0, stream>>>(packed, bstart, col, rowptr, dinv, N);

    // layer 1
    k_xw1<<<g1((long long)N * F), BS, 0, stream>>>(x, W1, buf0, N);
    k_gather<<<g1((long long)N * 4), BS, 0, stream>>>(buf0, rowptr, col, dinv, b1,
                                                      batch, buf1, sum1, max1, cnt,
                                                      N, E, /*store=*/1, /*do_cnt=*/1);
    // layer 2
    k_gemm2<<<g1((long long)N * F), BS, 0, stream>>>(buf1, W2, buf0, N);
    k_gather<<<g1((long long)N * 4), BS, 0, stream>>>(buf0, rowptr, col, dinv, b2,
                                                      batch, buf1, sum2, max2, cnt,
                                                      N, E, /*store=*/0, /*do_cnt=*/0);

    // MLP head
    k_mlp<<<B, 64, 0, stream>>>(sum1, max1, sum2, max2, cnt,
                                LW1, Lb1, LW2, Lb2, out, OUTD);
}

// Round 8
// 342.063 us; speedup vs baseline: 3.6344x; 1.4094x over previous
//
#include <hip/hip_runtime.h>
#include <hip/hip_fp16.h>

// Topology encoder: 2-layer GCN (N=100k nodes, E=3.2M edges) + max/mean pool
// over B=64 graphs + 2-layer MLP. fp32 in/out; node features stored fp16
// (64B rows = 1 cache line) with fp32 accumulation.
//
// CSR-by-dst built per call with ZERO global atomics:
//   k_histB  : per-block LDS bucket histogram -> bcnt[bucket][block] (stores)
//   k_rowscan: per-bucket exclusive scan of bcnt row -> private offsets + tot
//   k_bscan  : single-block scan of bucket totals -> bstart
//   k_bin    : LDS cursors (private per block) -> packed, contiguous runs
//   k_place2 : per-bucket LDS degree count + scan -> rowptr, dinv, col
// Layers are gathers (no fp32 scatter atomics). Pool atomics wave-reduced.

#define F 32
#define POOLD 64
#define BKT 512           // nodes per bucket (log2 = 9); place2 blockDim == BKT
#define BKTL2 9
#define EPB 8192          // edges per k_histB/k_bin block
#define MAXBUCK 256       // supports N <= 131072

typedef __attribute__((ext_vector_type(8))) _Float16 half8;

// ---- per-block LDS bucket histogram; direct store to bcnt[b][blk] ----
__global__ void k_histB(const int* __restrict__ ei, int* __restrict__ bcnt,
                        int e, int nbuck, int nblk) {
    __shared__ int h[MAXBUCK];
    for (int b = threadIdx.x; b < nbuck; b += 256) h[b] = 0;
    __syncthreads();
    int base = blockIdx.x * EPB;
#pragma unroll
    for (int k = 0; k < EPB / 1024; ++k) {
        int i = base + (k * 256 + threadIdx.x) * 4;
        if (i + 4 <= e) {
            int4 d4 = *reinterpret_cast<const int4*>(ei + e + i);
            atomicAdd(&h[d4.x >> BKTL2], 1);
            atomicAdd(&h[d4.y >> BKTL2], 1);
            atomicAdd(&h[d4.z >> BKTL2], 1);
            atomicAdd(&h[d4.w >> BKTL2], 1);
        } else {
            for (int j = i; j < e && j < i + 4; ++j)
                atomicAdd(&h[ei[e + j] >> BKTL2], 1);
        }
    }
    __syncthreads();
    for (int b = threadIdx.x; b < nbuck; b += 256)
        bcnt[b * nblk + blockIdx.x] = h[b];
}

// ---- per bucket: exclusive scan of bcnt row (in place) + row total ----
__global__ void k_rowscan(int* __restrict__ bcnt, int* __restrict__ tot, int nblk) {
    __shared__ int lds[256];
    int* row = bcnt + (size_t)blockIdx.x * nblk;
    int t = threadIdx.x;
    int running = 0;
    for (int chunk = 0; chunk < nblk; chunk += 256) {
        int idx = chunk + t;
        int v = (idx < nblk) ? row[idx] : 0;
        lds[t] = v;
        __syncthreads();
        int val = v;
        for (int off = 1; off < 256; off <<= 1) {
            int other = (t >= off) ? lds[t - off] : 0;
            __syncthreads();
            val += other;
            lds[t] = val;
            __syncthreads();
        }
        if (idx < nblk) row[idx] = running + val - v;  // exclusive
        running += lds[255];
        __syncthreads();
    }
    if (t == 0) tot[blockIdx.x] = running;
}

// ---- single block: scan bucket totals -> bstart (nbuck <= 256) ----
__global__ void k_bscan(const int* __restrict__ tot, int* __restrict__ bstart,
                        int nbuck, int e) {
    __shared__ int lds[256];
    int t = threadIdx.x;
    int v = (t < nbuck) ? tot[t] : 0;
    lds[t] = v;
    __syncthreads();
    int val = v;
    for (int off = 1; off < 256; off <<= 1) {
        int other = (t >= off) ? lds[t - off] : 0;
        __syncthreads();
        val += other;
        lds[t] = val;
        __syncthreads();
    }
    if (t < nbuck) bstart[t] = val - v;  // exclusive
    if (t == 0) bstart[nbuck] = e;
}

// ---- partition edges into private per-(bucket,block) runs; LDS cursors ----
__global__ void k_bin(const int* __restrict__ ei, const int* __restrict__ bstart,
                      const int* __restrict__ bcnt, int* __restrict__ packed,
                      int e, int nbuck, int nblk) {
    __shared__ int cur[MAXBUCK];
    for (int b = threadIdx.x; b < nbuck; b += 256)
        cur[b] = bstart[b] + bcnt[b * nblk + blockIdx.x];
    __syncthreads();
    int base = blockIdx.x * EPB;
#pragma unroll
    for (int k = 0; k < EPB / 1024; ++k) {
        int i = base + (k * 256 + threadIdx.x) * 4;
        if (i + 4 <= e) {
            int4 s4 = *reinterpret_cast<const int4*>(ei + i);
            int4 d4 = *reinterpret_cast<const int4*>(ei + e + i);
            int p0 = atomicAdd(&cur[d4.x >> BKTL2], 1);
            int p1 = atomicAdd(&cur[d4.y >> BKTL2], 1);
            int p2 = atomicAdd(&cur[d4.z >> BKTL2], 1);
            int p3 = atomicAdd(&cur[d4.w >> BKTL2], 1);
            packed[p0] = (s4.x << BKTL2) | (d4.x & (BKT - 1));
            packed[p1] = (s4.y << BKTL2) | (d4.y & (BKT - 1));
            packed[p2] = (s4.z << BKTL2) | (d4.z & (BKT - 1));
            packed[p3] = (s4.w << BKTL2) | (d4.w & (BKT - 1));
        } else {
            for (int j = i; j < e && j < i + 4; ++j) {
                int s = ei[j], d = ei[e + j];
                int p = atomicAdd(&cur[d >> BKTL2], 1);
                packed[p] = (s << BKTL2) | (d & (BKT - 1));
            }
        }
    }
}

// ---- per bucket (512 threads): LDS degree+scan -> rowptr/dinv; place col ----
__global__ void k_place2(const int* __restrict__ packed, const int* __restrict__ bstart,
                         int* __restrict__ col, int* __restrict__ rp,
                         float* __restrict__ dinv, int n) {
    __shared__ int deg[BKT];
    __shared__ int sc[BKT];
    __shared__ int cur[BKT];
    int t = threadIdx.x;
    deg[t] = 0;
    __syncthreads();
    int start = bstart[blockIdx.x];
    int end = bstart[blockIdx.x + 1];
    for (int i = start + t; i < end; i += BKT)
        atomicAdd(&deg[packed[i] & (BKT - 1)], 1);
    __syncthreads();
    int d0 = deg[t];
    sc[t] = d0;
    __syncthreads();
    int val = d0;
    for (int off = 1; off < BKT; off <<= 1) {
        int other = (t >= off) ? sc[t - off] : 0;
        __syncthreads();
        val += other;
        sc[t] = val;
        __syncthreads();
    }
    int node = blockIdx.x * BKT + t;
    int ex = start + val - d0;   // bucket start + exclusive prefix
    if (node < n) {
        rp[node] = ex;
        dinv[node] = rsqrtf((float)d0 + 1.0f);
    }
    cur[t] = ex;
    __syncthreads();
    for (int i = start + t; i < end; i += BKT) {
        int u = packed[i];
        int p = atomicAdd(&cur[u & (BKT - 1)], 1);
        col[p] = u >> BKTL2;
    }
}

// ---- h0 = x @ W1  (K=3), fp16 out ----
__global__ void k_xw1(const float* __restrict__ x, const float* __restrict__ W1,
                      _Float16* __restrict__ h0, int n) {
    int i = blockIdx.x * blockDim.x + threadIdx.x;
    if (i >= n * F) return;
    int node = i >> 5, f = i & (F - 1);
    float x0 = x[node * 3 + 0], x1 = x[node * 3 + 1], x2 = x[node * 3 + 2];
    h0[i] = (_Float16)(x0 * W1[f] + x1 * W1[F + f] + x2 * W1[2 * F + f]);
}

// ---- g = h @ W2  (32x32), fp16 in/out, fp32 accumulate ----
__global__ void k_gemm2(const _Float16* __restrict__ h, const float* __restrict__ W2,
                        _Float16* __restrict__ g, int n) {
    int i = blockIdx.x * blockDim.x + threadIdx.x;
    if (i >= n * F) return;
    int node = i >> 5, f = i & (F - 1);
    const _Float16* row = h + (size_t)node * F;
    float acc = 0.0f;
#pragma unroll
    for (int k = 0; k < F; ++k) acc += (float)row[k] * W2[k * F + f];
    g[i] = (_Float16)acc;
}

// ---- fused gather conv + bias + relu + pool; 4 threads/node (8 feats each) ----
__global__ void k_gather(const _Float16* __restrict__ hin, const int* __restrict__ rp,
                         const int* __restrict__ col, const float* __restrict__ dinv,
                         const float* __restrict__ bias, const int* __restrict__ batch,
                         _Float16* __restrict__ hout,
                         float* __restrict__ psum, float* __restrict__ pmax,
                         float* __restrict__ cnt, int n, int ne, int store, int do_cnt) {
    int t = blockIdx.x * blockDim.x + threadIdx.x;
    int node = t >> 2, q = t & 3;
    if (node >= n) return;
    int start = rp[node];
    int end = (node + 1 < n) ? rp[node + 1] : ne;
    float dv = dinv[node];

    half8 hv = *reinterpret_cast<const half8*>(hin + (size_t)node * F + q * 8);
    float dvv = dv * dv;
    float acc[8];
#pragma unroll
    for (int j = 0; j < 8; ++j) acc[j] = (float)hv[j] * dvv;

    int e = start;
    for (; e + 4 <= end; e += 4) {
        int s0 = col[e + 0], s1 = col[e + 1], s2 = col[e + 2], s3 = col[e + 3];
        float w0 = dinv[s0] * dv, w1 = dinv[s1] * dv,
              w2 = dinv[s2] * dv, w3 = dinv[s3] * dv;
        half8 v0 = *reinterpret_cast<const half8*>(hin + (size_t)s0 * F + q * 8);
        half8 v1 = *reinterpret_cast<const half8*>(hin + (size_t)s1 * F + q * 8);
        half8 v2 = *reinterpret_cast<const half8*>(hin + (size_t)s2 * F + q * 8);
        half8 v3 = *reinterpret_cast<const half8*>(hin + (size_t)s3 * F + q * 8);
#pragma unroll
        for (int j = 0; j < 8; ++j)
            acc[j] += (float)v0[j] * w0 + (float)v1[j] * w1 +
                      (float)v2[j] * w2 + (float)v3[j] * w3;
    }
    for (; e < end; ++e) {
        int s = col[e];
        float wv = dinv[s] * dv;
        half8 v = *reinterpret_cast<const half8*>(hin + (size_t)s * F + q * 8);
#pragma unroll
        for (int j = 0; j < 8; ++j) acc[j] += (float)v[j] * wv;
    }

    float vv[8];
#pragma unroll
    for (int j = 0; j < 8; ++j) vv[j] = fmaxf(acc[j] + bias[q * 8 + j], 0.0f);
    if (store) {
        half8 o;
#pragma unroll
        for (int j = 0; j < 8; ++j) o[j] = (_Float16)vv[j];
        *reinterpret_cast<half8*>(hout + (size_t)node * F + q * 8) = o;
    }

    int b = batch[node];
    int lane = threadIdx.x & 63;
    int bFirst = __shfl(b, 0);
    int bLast  = __shfl(b, 63);
    if (bFirst == bLast) {
        float sv[8], mv[8];
#pragma unroll
        for (int j = 0; j < 8; ++j) { sv[j] = vv[j]; mv[j] = vv[j]; }
        for (int off = 4; off < 64; off <<= 1) {
#pragma unroll
            for (int j = 0; j < 8; ++j) {
                sv[j] += __shfl_down(sv[j], off);
                mv[j] = fmaxf(mv[j], __shfl_down(mv[j], off));
            }
        }
        if (lane < 4) {
            float* ps = psum + b * F + lane * 8;
            int* pm = reinterpret_cast<int*>(pmax + b * F + lane * 8);
#pragma unroll
            for (int j = 0; j < 8; ++j) {
                atomicAdd(ps + j, sv[j]);
                atomicMax(pm + j, __float_as_int(mv[j]));  // vv >= 0
            }
            if (do_cnt && lane == 0) atomicAdd(&cnt[b], 16.0f);
        }
    } else {
        float* ps = psum + b * F + q * 8;
        int* pm = reinterpret_cast<int*>(pmax + b * F + q * 8);
#pragma unroll
        for (int j = 0; j < 8; ++j) {
            atomicAdd(ps + j, vv[j]);
            atomicMax(pm + j, __float_as_int(vv[j]));
        }
        if (do_cnt && q == 0) atomicAdd(&cnt[b], 1.0f);
    }
}

// ---- fused MLP head: one block per graph (64 threads) ----
__global__ void k_mlp(const float* __restrict__ sum1, const float* __restrict__ max1,
                      const float* __restrict__ sum2, const float* __restrict__ max2,
                      const float* __restrict__ cnt,
                      const float* __restrict__ LW1, const float* __restrict__ Lb1,
                      const float* __restrict__ LW2, const float* __restrict__ Lb2,
                      float* __restrict__ out, int outd) {
    __shared__ float zs[POOLD];
    int b = blockIdx.x, j = threadIdx.x;  // blockDim.x == 64
    float invc = 1.0f / fmaxf(cnt[b], 1.0f);
    float acc = Lb1[j];
#pragma unroll
    for (int i = 0; i < POOLD; ++i) {
        float s;
        if (i < F) s = max1[b * F + i] + max2[b * F + i];
        else       s = (sum1[b * F + i - F] + sum2[b * F + i - F]) * invc;
        acc += s * LW1[i * POOLD + j];
    }
    zs[j] = fmaxf(acc, 0.0f);
    __syncthreads();
    if (j < outd) {
        float a2 = Lb2[j];
#pragma unroll
        for (int jj = 0; jj < POOLD; ++jj) a2 += zs[jj] * LW2[jj * outd + j];
        out[b * outd + j] = a2;
    }
}

extern "C" void kernel_launch(void* const* d_in, const int* in_sizes, int n_in,
                              void* d_out, int out_size, void* d_ws, size_t ws_size,
                              hipStream_t stream) {
    const float* x    = (const float*)d_in[0];
    const int*   ei   = (const int*)d_in[1];
    const int*   batch= (const int*)d_in[2];
    const float* W1   = (const float*)d_in[3];
    const float* b1   = (const float*)d_in[4];
    const float* W2   = (const float*)d_in[5];
    const float* b2   = (const float*)d_in[6];
    const float* LW1  = (const float*)d_in[7];
    const float* Lb1  = (const float*)d_in[8];
    const float* LW2  = (const float*)d_in[9];
    const float* Lb2  = (const float*)d_in[10];
    float* out = (float*)d_out;

    const int N = in_sizes[0] / 3;
    const int E = in_sizes[1] / 2;
    const int OUTD = in_sizes[10];
    const int B = out_size / OUTD;
    const int poolsz = 4 * B * F + B;
    const int NBUCK = (N + BKT - 1) / BKT;      // <= MAXBUCK
    const int NBLK = (E + EPB - 1) / EPB;

    // ---- workspace layout ----
    char* p = (char*)d_ws;
    float* pools= (float*)p;          p += (size_t)poolsz * 4;
    int* bcnt   = (int*)p;            p += (size_t)NBUCK * NBLK * 4;
    int* tot    = (int*)p;            p += (size_t)MAXBUCK * 4;
    int* bstart = (int*)p;            p += (size_t)(NBUCK + 1) * 4;
    int* rowptr = (int*)p;            p += (size_t)N * 4;
    int* col    = (int*)p;            p += (size_t)E * 4;
    float* dinv = (float*)p;          p += (size_t)N * 4;
    _Float16* buf0 = (_Float16*)p;    p += (size_t)N * F * 2;
    _Float16* buf1 = (_Float16*)p;    p += (size_t)N * F * 2;
    int* packed = (int*)buf0;         // aliased over buf0+buf1 (E*4 == N*F*4 B);
                                      // consumed by k_place2 before buf0/buf1 written
    float* sum1 = pools;
    float* max1 = sum1 + B * F;
    float* sum2 = max1 + B * F;
    float* max2 = sum2 + B * F;
    float* cnt  = max2 + B * F;

    const int BS = 256;
    auto g1 = [&](long long n) { return (int)((n + BS - 1) / BS); };

    // CSR build + norms (zero global atomics)
    hipMemsetAsync(pools, 0, (size_t)poolsz * 4, stream);
    k_histB<<<NBLK, BS, 0, stream>>>(ei, bcnt, E, NBUCK, NBLK);
    k_rowscan<<<NBUCK, 256, 0, stream>>>(bcnt, tot, NBLK);
    k_bscan<<<1, 256, 0, stream>>>(tot, bstart, NBUCK, E);
    k_bin<<<NBLK, BS, 0, stream>>>(ei, bstart, bcnt, packed, E, NBUCK, NBLK);
    k_place2<<<NBUCK, BKT, 0, stream>>>(packed, bstart, col, rowptr, dinv, N);

    // layer 1
    k_xw1<<<g1((long long)N * F), BS, 0, stream>>>(x, W1, buf0, N);
    k_gather<<<g1((long long)N * 4), BS, 0, stream>>>(buf0, rowptr, col, dinv, b1,
                                                      batch, buf1, sum1, max1, cnt,
                                                      N, E, /*store=*/1, /*do_cnt=*/1);
    // layer 2
    k_gemm2<<<g1((long long)N * F), BS, 0, stream>>>(buf1, W2, buf0, N);
    k_gather<<<g1((long long)N * 4), BS, 0, stream>>>(buf0, rowptr, col, dinv, b2,
                                                      batch, buf1, sum2, max2, cnt,
                                                      N, E, /*store=*/0, /*do_cnt=*/0);

    // MLP head
    k_mlp<<<B, 64, 0, stream>>>(sum1, max1, sum2, max2, cnt,
                                LW1, Lb1, LW2, Lb2, out, OUTD);
}